// Round 1
// baseline (419.846 us; speedup 1.0000x reference)
//
#include <hip/hip_runtime.h>
#include <stdint.h>

#define SS 64
#define NN 4096
#define FF 32
#define HH 64
#define OO 2
#define G3 192

typedef float f32x4 __attribute__((ext_vector_type(4)));
typedef short bf16x8 __attribute__((ext_vector_type(8)));
typedef unsigned short u16x8 __attribute__((ext_vector_type(8)));

__device__ __forceinline__ unsigned short f2bf(float f) {
  union { float f; uint32_t u; } v; v.f = f;
  uint32_t u = v.u;
  uint32_t r = (u + 0x7FFFu + ((u >> 16) & 1u)) >> 16;
  return (unsigned short)r;
}
__device__ __forceinline__ float bf2f(unsigned short s) {
  union { uint32_t u; float f; } v; v.u = ((uint32_t)s) << 16;
  return v.f;
}

// ---------------- adj f32 -> bf16 ----------------
__global__ __launch_bounds__(256) void k_cvt(const float* __restrict__ a,
                                             unsigned short* __restrict__ o_, int n4) {
  int id = blockIdx.x * 256 + threadIdx.x;
  int stride = gridDim.x * 256;
  for (int i = id; i < n4; i += stride) {
    float4 v = ((const float4*)a)[i];
    ushort4 r;
    r.x = f2bf(v.x); r.y = f2bf(v.y); r.z = f2bf(v.z); r.w = f2bf(v.w);
    ((ushort4*)o_)[i] = r;
  }
}

// ---------------- support = x@W1+b1, written transposed: Bt[s*64+h][j] bf16 ----------------
__global__ __launch_bounds__(256) void k_support(const float* __restrict__ x,
                                                 const float* __restrict__ W1,
                                                 const float* __restrict__ b1,
                                                 unsigned short* __restrict__ Bt) {
  __shared__ float xl[64][33];
  __shared__ float w1l[32 * 64];
  __shared__ float b1l[64];
  int bs = blockIdx.x;
  int s = bs >> 6, jb = (bs & 63) << 6;
  int tid = threadIdx.x;
  const float4* xg = (const float4*)(x + ((size_t)s * NN + jb) * FF);
  #pragma unroll
  for (int i = 0; i < 2; ++i) {
    int idx = tid + i * 256;
    float4 v = xg[idx];
    int j = idx >> 3, f = (idx & 7) << 2;
    xl[j][f] = v.x; xl[j][f + 1] = v.y; xl[j][f + 2] = v.z; xl[j][f + 3] = v.w;
  }
  #pragma unroll
  for (int i = 0; i < 2; ++i) {
    int idx = tid + i * 256;
    float4 v = ((const float4*)W1)[idx];
    w1l[idx * 4] = v.x; w1l[idx * 4 + 1] = v.y; w1l[idx * 4 + 2] = v.z; w1l[idx * 4 + 3] = v.w;
  }
  if (tid < 64) b1l[tid] = b1[tid];
  __syncthreads();
  int jj = tid & 63, hq = tid >> 6;
  unsigned short* outb = Bt + (size_t)(s * HH) * NN + jb + jj;
  #pragma unroll
  for (int hh = 0; hh < 16; ++hh) {
    int h = hq * 16 + hh;
    float acc = b1l[h];
    #pragma unroll
    for (int f = 0; f < FF; ++f) acc += xl[jj][f] * w1l[f * 64 + h];
    outb[(size_t)h * NN] = f2bf(acc);
  }
}

// ---------------- shared MFMA GEMM core: C[i][c] = sum_j A[i][j]*B[c][j], both k-major, ld=4096 ----------------
__device__ __forceinline__ void gemm_core(const unsigned short* __restrict__ A,
                                          const unsigned short* __restrict__ B,
                                          int i0, int c0, int k0base, int ksteps,
                                          f32x4 acc[4][4],
                                          unsigned short* Als, unsigned short* Bls) {
  const int tid = threadIdx.x;
  const int w = tid >> 6, l = tid & 63;
  const int srow = (l >> 2);
  const int scol = (l & 3) * 16;   // bytes within 64B row
  for (int kt = 0; kt < ksteps; ++kt) {
    int k0 = k0base + kt * 32;
    #pragma unroll
    for (int q = 0; q < 2; ++q) {
      int r = w * 32 + q * 16 + srow;
      const char* ga = (const char*)(A + (size_t)(i0 + r) * 4096 + k0) + scol;
      __builtin_amdgcn_global_load_lds(
          (const __attribute__((address_space(1))) void*)ga,
          (__attribute__((address_space(3))) void*)((char*)Als + w * 2048 + q * 1024),
          16, 0, 0);
      const char* gb = (const char*)(B + (size_t)(c0 + r) * 4096 + k0) + scol;
      __builtin_amdgcn_global_load_lds(
          (const __attribute__((address_space(1))) void*)gb,
          (__attribute__((address_space(3))) void*)((char*)Bls + w * 2048 + q * 1024),
          16, 0, 0);
    }
    __syncthreads();
    const int wr = w >> 1, wc = w & 1;
    bf16x8 af[4], bff[4];
    #pragma unroll
    for (int m = 0; m < 4; ++m)
      af[m] = *(const bf16x8*)(Als + (wr * 64 + m * 16 + (l & 15)) * 32 + (l >> 4) * 8);
    #pragma unroll
    for (int n = 0; n < 4; ++n)
      bff[n] = *(const bf16x8*)(Bls + (wc * 64 + n * 16 + (l & 15)) * 32 + (l >> 4) * 8);
    #pragma unroll
    for (int m = 0; m < 4; ++m)
      #pragma unroll
      for (int n = 0; n < 4; ++n)
        acc[m][n] = __builtin_amdgcn_mfma_f32_16x16x32_bf16(af[m], bff[n], acc[m][n], 0, 0, 0);
    __syncthreads();
  }
}

// ---------------- GEMM1: Hrelu[i][s*64+h] = relu(adj @ support) bf16 ----------------
__global__ __launch_bounds__(256) void k_gemm1(const unsigned short* __restrict__ A,
                                               const unsigned short* __restrict__ B,
                                               unsigned short* __restrict__ Crelu) {
  __shared__ unsigned short Als[128 * 32], Bls[128 * 32];
  int id = blockIdx.x;
  int wg = (id & 7) * 128 + (id >> 3);   // XCD swizzle, bijective (1024 = 8*128)
  int bi = wg >> 5, bc = wg & 31;
  int i0 = bi * 128, c0 = bc * 128;
  f32x4 acc[4][4];
  #pragma unroll
  for (int m = 0; m < 4; ++m)
    #pragma unroll
    for (int n = 0; n < 4; ++n) acc[m][n] = {0.f, 0.f, 0.f, 0.f};
  gemm_core(A, B, i0, c0, 0, 128, acc, Als, Bls);
  int l = threadIdx.x & 63, w = threadIdx.x >> 6;
  int wr = w >> 1, wc = w & 1;
  int rbase = i0 + wr * 64 + (l >> 4) * 4;
  int cbase = c0 + wc * 64 + (l & 15);
  #pragma unroll
  for (int m = 0; m < 4; ++m)
    #pragma unroll
    for (int n = 0; n < 4; ++n)
      #pragma unroll
      for (int r = 0; r < 4; ++r) {
        float v = acc[m][n][r];
        v = v > 0.f ? v : 0.f;
        Crelu[(size_t)(rbase + m * 16 + r) * 4096 + cbase + n * 16] = f2bf(v);
      }
}

// ---------------- support2: B2t[s*2+o][i] = relu_h . W2 + b2 (bf16) ----------------
__global__ __launch_bounds__(256) void k_support2(const unsigned short* __restrict__ Hr,
                                                 const float* __restrict__ W2,
                                                 const float* __restrict__ b2,
                                                 unsigned short* __restrict__ B2t) {
  __shared__ float w2l[128];
  __shared__ float b2l[2];
  int s = blockIdx.x >> 4, ib = blockIdx.x & 15;
  int tid = threadIdx.x;
  if (tid < 128) w2l[tid] = W2[tid];
  if (tid < 2) b2l[tid] = b2[tid];
  __syncthreads();
  int i = ib * 256 + tid;
  const u16x8* hp = (const u16x8*)(Hr + (size_t)i * 4096 + s * 64);
  float acc0 = b2l[0], acc1 = b2l[1];
  #pragma unroll
  for (int q = 0; q < 8; ++q) {
    u16x8 hv = hp[q];
    #pragma unroll
    for (int e = 0; e < 8; ++e) {
      float f = bf2f((unsigned short)hv[e]);
      acc0 += f * w2l[(q * 8 + e) * 2];
      acc1 += f * w2l[(q * 8 + e) * 2 + 1];
    }
  }
  B2t[(size_t)(s * 2 + 0) * 4096 + i] = f2bf(acc0);
  B2t[(size_t)(s * 2 + 1) * 4096 + i] = f2bf(acc1);
}

// ---------------- GEMM2 split-K: Gp[ks][i][c2] partial f32 ----------------
__global__ __launch_bounds__(256) void k_gemm2(const unsigned short* __restrict__ A,
                                               const unsigned short* __restrict__ B,
                                               float* __restrict__ Gp) {
  __shared__ unsigned short Als[128 * 32], Bls[128 * 32];
  int id = blockIdx.x;
  int bi = id & 31, ks = id >> 5;
  int i0 = bi * 128;
  f32x4 acc[4][4];
  #pragma unroll
  for (int m = 0; m < 4; ++m)
    #pragma unroll
    for (int n = 0; n < 4; ++n) acc[m][n] = {0.f, 0.f, 0.f, 0.f};
  gemm_core(A, B, i0, 0, ks * 512, 16, acc, Als, Bls);
  float* outp = Gp + (size_t)ks * 4096 * 128;
  int l = threadIdx.x & 63, w = threadIdx.x >> 6;
  int wr = w >> 1, wc = w & 1;
  int rbase = i0 + wr * 64 + (l >> 4) * 4;
  int cbase = wc * 64 + (l & 15);
  #pragma unroll
  for (int m = 0; m < 4; ++m)
    #pragma unroll
    for (int n = 0; n < 4; ++n)
      #pragma unroll
      for (int r = 0; r < 4; ++r)
        outp[(size_t)(rbase + m * 16 + r) * 128 + cbase + n * 16] = acc[m][n][r];
}

// ---------------- reduce split-K + log_softmax -> R[s][i*2+o] f32 ----------------
__global__ __launch_bounds__(256) void k_lsm(const float* __restrict__ Gp,
                                             float* __restrict__ Rm) {
  __shared__ float Gacc[32][130];
  int i0 = blockIdx.x * 32;
  int tid = threadIdx.x;
  float4 v[4];
  #pragma unroll
  for (int i = 0; i < 4; ++i) v[i] = {0.f, 0.f, 0.f, 0.f};
  for (int ks = 0; ks < 8; ++ks) {
    const float4* gp4 = ((const float4*)Gp) + (size_t)ks * 131072 + (size_t)i0 * 32;
    #pragma unroll
    for (int i = 0; i < 4; ++i) {
      float4 t = gp4[tid + i * 256];
      v[i].x += t.x; v[i].y += t.y; v[i].z += t.z; v[i].w += t.w;
    }
  }
  #pragma unroll
  for (int i = 0; i < 4; ++i) {
    int f4i = tid + i * 256, row = f4i >> 5, c = (f4i & 31) * 4;
    Gacc[row][c] = v[i].x; Gacc[row][c + 1] = v[i].y;
    Gacc[row][c + 2] = v[i].z; Gacc[row][c + 3] = v[i].w;
  }
  __syncthreads();
  #pragma unroll
  for (int j = 0; j < 8; ++j) {
    int p = j * 256 + tid;
    int ii = p & 31, s = p >> 5;
    float g0 = Gacc[ii][s * 2], g1 = Gacc[ii][s * 2 + 1];
    float m = fmaxf(g0, g1);
    float lse = m + logf(expf(g0 - m) + expf(g1 - m));
    float2 o_; o_.x = g0 - lse; o_.y = g1 - lse;
    *((float2*)(Rm + (size_t)s * 8192 + (size_t)(i0 + ii) * 2)) = o_;
  }
}

// ---------------- gi0 partial: part[ks][t][g] = R[t] . Wih0[g] over c-range ----------------
__global__ __launch_bounds__(256) void k_gi0(const float* __restrict__ Rm,
                                             const float* __restrict__ Wih0,
                                             float* __restrict__ part) {
  __shared__ float4 Wl[4 * 128];
  int gb = blockIdx.x % 48, ks = blockIdx.x / 48;
  int c0 = ks * 512;
  int tid = threadIdx.x;
  #pragma unroll
  for (int i = 0; i < 2; ++i) {
    int idx = tid + i * 256;
    int g = idx >> 7, c4 = idx & 127;
    Wl[g * 128 + c4] = ((const float4*)(Wih0 + (size_t)(gb * 4 + g) * 8192 + c0))[c4];
  }
  __syncthreads();
  int w = tid >> 6, lane = tid & 63;
  for (int pass = 0; pass < 16; ++pass) {
    int t = pass * 4 + w;
    float a0 = 0.f, a1 = 0.f, a2 = 0.f, a3 = 0.f;
    const float4* rg = (const float4*)(Rm + (size_t)t * 8192 + c0);
    #pragma unroll
    for (int i = 0; i < 2; ++i) {
      int c4 = i * 64 + lane;
      float4 r4 = rg[c4];
      float4 w0 = Wl[c4], w1 = Wl[128 + c4], w2 = Wl[256 + c4], w3 = Wl[384 + c4];
      a0 += r4.x * w0.x + r4.y * w0.y + r4.z * w0.z + r4.w * w0.w;
      a1 += r4.x * w1.x + r4.y * w1.y + r4.z * w1.z + r4.w * w1.w;
      a2 += r4.x * w2.x + r4.y * w2.y + r4.z * w2.z + r4.w * w2.w;
      a3 += r4.x * w3.x + r4.y * w3.y + r4.z * w3.z + r4.w * w3.w;
    }
    #pragma unroll
    for (int off = 1; off < 64; off <<= 1) {
      a0 += __shfl_xor(a0, off);
      a1 += __shfl_xor(a1, off);
      a2 += __shfl_xor(a2, off);
      a3 += __shfl_xor(a3, off);
    }
    if (lane == 0) {
      float4 o_; o_.x = a0; o_.y = a1; o_.z = a2; o_.w = a3;
      *((float4*)(part + ((size_t)ks * 64 + t) * 192 + gb * 4)) = o_;
    }
  }
}

__global__ __launch_bounds__(256) void k_gi0red(const float* __restrict__ part,
                                                const float* __restrict__ bih0,
                                                float* __restrict__ gi0) {
  int idx = blockIdx.x * 256 + threadIdx.x;
  if (idx < 12288) {
    float s_ = bih0[idx % 192];
    for (int ks = 0; ks < 16; ++ks) s_ += part[ks * 12288 + idx];
    gi0[idx] = s_;
  }
}

// ---------------- fused 2-layer GRU, batch 1, weights in VGPRs ----------------
__global__ __launch_bounds__(192) void k_gru(const float* __restrict__ gi0,
                                             const float* __restrict__ Whh0,
                                             const float* __restrict__ bhh0,
                                             const float* __restrict__ Wih1,
                                             const float* __restrict__ Whh1,
                                             const float* __restrict__ bih1,
                                             const float* __restrict__ bhh1,
                                             float* __restrict__ out) {
  __shared__ float h0s[64], h1s[64], ys0s[64], gA[192], uA[192], vA[192];
  int g = threadIdx.x;
  float w0[64], wi1[64], wh1[64];
  #pragma unroll
  for (int k = 0; k < 16; ++k) {
    float4 t0 = ((const float4*)(Whh0 + (size_t)g * 64))[k];
    float4 t1 = ((const float4*)(Wih1 + (size_t)g * 64))[k];
    float4 t2 = ((const float4*)(Whh1 + (size_t)g * 64))[k];
    w0[k * 4] = t0.x; w0[k * 4 + 1] = t0.y; w0[k * 4 + 2] = t0.z; w0[k * 4 + 3] = t0.w;
    wi1[k * 4] = t1.x; wi1[k * 4 + 1] = t1.y; wi1[k * 4 + 2] = t1.z; wi1[k * 4 + 3] = t1.w;
    wh1[k * 4] = t2.x; wh1[k * 4 + 1] = t2.y; wh1[k * 4 + 2] = t2.z; wh1[k * 4 + 3] = t2.w;
  }
  float bh0 = bhh0[g], bi1 = bih1[g], bh1 = bhh1[g];
  if (g < 64) { h0s[g] = 0.f; h1s[g] = 0.f; }
  __syncthreads();
  for (int t = 0; t < 64; ++t) {
    float a0 = 0.f, a1 = 0.f, a2 = 0.f, a3 = 0.f;
    #pragma unroll
    for (int k = 0; k < 16; ++k) {
      float4 h4 = *(const float4*)&h0s[k * 4];
      a0 += w0[k * 4] * h4.x; a1 += w0[k * 4 + 1] * h4.y;
      a2 += w0[k * 4 + 2] * h4.z; a3 += w0[k * 4 + 3] * h4.w;
    }
    float gh = (a0 + a1) + (a2 + a3) + bh0;
    float giv = gi0[t * 192 + g];
    gA[g] = (g < 128) ? (giv + gh) : gh;
    __syncthreads();
    if (g < 64) {
      float r = 1.f / (1.f + expf(-gA[g]));
      float z = 1.f / (1.f + expf(-gA[g + 64]));
      float inn = gi0[t * 192 + 128 + g];
      float n = tanhf(inn + r * gA[g + 128]);
      float hnew = (1.f - z) * n + z * h0s[g];
      h0s[g] = hnew; ys0s[g] = hnew;
    }
    __syncthreads();
    float b0 = 0.f, b1_ = 0.f, b2_ = 0.f, b3 = 0.f;
    float c0 = 0.f, c1 = 0.f, c2 = 0.f, c3 = 0.f;
    #pragma unroll
    for (int k = 0; k < 16; ++k) {
      float4 y4 = *(const float4*)&ys0s[k * 4];
      float4 h4 = *(const float4*)&h1s[k * 4];
      b0 += wi1[k * 4] * y4.x; b1_ += wi1[k * 4 + 1] * y4.y;
      b2_ += wi1[k * 4 + 2] * y4.z; b3 += wi1[k * 4 + 3] * y4.w;
      c0 += wh1[k * 4] * h4.x; c1 += wh1[k * 4 + 1] * h4.y;
      c2 += wh1[k * 4 + 2] * h4.z; c3 += wh1[k * 4 + 3] * h4.w;
    }
    uA[g] = (b0 + b1_) + (b2_ + b3) + bi1;
    vA[g] = (c0 + c1) + (c2 + c3) + bh1;
    __syncthreads();
    if (g < 64) {
      float r = 1.f / (1.f + expf(-(uA[g] + vA[g])));
      float z = 1.f / (1.f + expf(-(uA[g + 64] + vA[g + 64])));
      float n = tanhf(uA[g + 128] + r * vA[g + 128]);
      float hnew = (1.f - z) * n + z * h1s[g];
      h1s[g] = hnew;
      out[t * 64 + g] = hnew;
    }
    __syncthreads();
  }
  if (g < 64) { out[4096 + g] = h0s[g]; out[4096 + 64 + g] = h1s[g]; }
}

extern "C" void kernel_launch(void* const* d_in, const int* in_sizes, int n_in,
                              void* d_out, int out_size, void* d_ws, size_t ws_size,
                              hipStream_t stream) {
  const float* x    = (const float*)d_in[0];
  const float* adj  = (const float*)d_in[1];
  const float* W1   = (const float*)d_in[2];
  const float* b1   = (const float*)d_in[3];
  const float* W2   = (const float*)d_in[4];
  const float* b2   = (const float*)d_in[5];
  const float* Wih0 = (const float*)d_in[6];
  const float* Whh0 = (const float*)d_in[7];
  const float* bih0 = (const float*)d_in[8];
  const float* bhh0 = (const float*)d_in[9];
  const float* Wih1 = (const float*)d_in[10];
  const float* Whh1 = (const float*)d_in[11];
  const float* bih1 = (const float*)d_in[12];
  const float* bhh1 = (const float*)d_in[13];
  float* out = (float*)d_out;

  char* ws = (char*)d_ws;
  // [0,32M): adjb ; [32M,64M): Bt, later reused for Gp/Rm/part/gi0/B2t ; [64M,96M): Hrelu
  unsigned short* adjb = (unsigned short*)ws;
  unsigned short* Bt   = (unsigned short*)(ws + 33554432);
  unsigned short* Hr   = (unsigned short*)(ws + 67108864);
  float* Gp   = (float*)(ws + 33554432);              // 16MB (Bt dead after gemm1)
  float* Rm   = (float*)(ws + 50331648);              // 2MB
  float* part = (float*)(ws + 52428800);              // 768KB
  float* gi0  = (float*)(ws + 53215232);              // 48KB
  unsigned short* B2t = (unsigned short*)(ws + 53264384); // 1MB

  k_cvt<<<4096, 256, 0, stream>>>(adj, adjb, 4194304);
  k_support<<<4096, 256, 0, stream>>>(x, W1, b1, Bt);
  k_gemm1<<<1024, 256, 0, stream>>>(adjb, Bt, Hr);
  k_support2<<<1024, 256, 0, stream>>>(Hr, W2, b2, B2t);
  k_gemm2<<<256, 256, 0, stream>>>(adjb, B2t, Gp);
  k_lsm<<<128, 256, 0, stream>>>(Gp, Rm);
  k_gi0<<<768, 256, 0, stream>>>(Rm, Wih0, part);
  k_gi0red<<<48, 256, 0, stream>>>(part, bih0, gi0);
  k_gru<<<1, 192, 0, stream>>>(gi0, Whh0, bhh0, Wih1, Whh1, bih1, bhh1, out);
}

// Round 2
// 342.239 us; speedup vs baseline: 1.2268x; 1.2268x over previous
//
#include <hip/hip_runtime.h>
#include <stdint.h>

#define SS 64
#define NN 4096
#define FF 32
#define HH 64
#define OO 2
#define G3 192

typedef float f32x4 __attribute__((ext_vector_type(4)));
typedef short bf16x8 __attribute__((ext_vector_type(8)));
typedef unsigned short u16x8 __attribute__((ext_vector_type(8)));

__device__ __forceinline__ unsigned short f2bf(float f) {
  union { float f; uint32_t u; } v; v.f = f;
  uint32_t u = v.u;
  uint32_t r = (u + 0x7FFFu + ((u >> 16) & 1u)) >> 16;
  return (unsigned short)r;
}
__device__ __forceinline__ float bf2f(unsigned short s) {
  union { uint32_t u; float f; } v; v.u = ((uint32_t)s) << 16;
  return v.f;
}

// ---------------- adj f32 -> bf16 ----------------
__global__ __launch_bounds__(256) void k_cvt(const float* __restrict__ a,
                                             unsigned short* __restrict__ o_, int n4) {
  int id = blockIdx.x * 256 + threadIdx.x;
  int stride = gridDim.x * 256;
  for (int i = id; i < n4; i += stride) {
    float4 v = ((const float4*)a)[i];
    ushort4 r;
    r.x = f2bf(v.x); r.y = f2bf(v.y); r.z = f2bf(v.z); r.w = f2bf(v.w);
    ((ushort4*)o_)[i] = r;
  }
}

// ---------------- support = x@W1+b1, written transposed: Bt[s*64+h][j] bf16 ----------------
__global__ __launch_bounds__(256) void k_support(const float* __restrict__ x,
                                                 const float* __restrict__ W1,
                                                 const float* __restrict__ b1,
                                                 unsigned short* __restrict__ Bt) {
  __shared__ float xl[64][33];
  __shared__ float w1l[32 * 64];
  __shared__ float b1l[64];
  int bs = blockIdx.x;
  int s = bs >> 6, jb = (bs & 63) << 6;
  int tid = threadIdx.x;
  const float4* xg = (const float4*)(x + ((size_t)s * NN + jb) * FF);
  #pragma unroll
  for (int i = 0; i < 2; ++i) {
    int idx = tid + i * 256;
    float4 v = xg[idx];
    int j = idx >> 3, f = (idx & 7) << 2;
    xl[j][f] = v.x; xl[j][f + 1] = v.y; xl[j][f + 2] = v.z; xl[j][f + 3] = v.w;
  }
  #pragma unroll
  for (int i = 0; i < 2; ++i) {
    int idx = tid + i * 256;
    float4 v = ((const float4*)W1)[idx];
    w1l[idx * 4] = v.x; w1l[idx * 4 + 1] = v.y; w1l[idx * 4 + 2] = v.z; w1l[idx * 4 + 3] = v.w;
  }
  if (tid < 64) b1l[tid] = b1[tid];
  __syncthreads();
  int jj = tid & 63, hq = tid >> 6;
  unsigned short* outb = Bt + (size_t)(s * HH) * NN + jb + jj;
  #pragma unroll
  for (int hh = 0; hh < 16; ++hh) {
    int h = hq * 16 + hh;
    float acc = b1l[h];
    #pragma unroll
    for (int f = 0; f < FF; ++f) acc += xl[jj][f] * w1l[f * 64 + h];
    outb[(size_t)h * NN] = f2bf(acc);
  }
}

// =====================================================================
// GEMM1: 256x256 tile, BK=64, 8 waves, double-buffered 8-phase schedule
// C[i][c] = relu(sum_j A[i][j]*B[c][j]), A/B k-major ld=4096 bf16
// LDS: 2 buf x (A[256][64] + B[256][64]) = 128 KiB, XOR-swizzled reads
// =====================================================================
#define SBAR()   asm volatile("s_barrier" ::: "memory")
#define VMCNT4() asm volatile("s_waitcnt vmcnt(4)" ::: "memory")
#define VMCNT0() asm volatile("s_waitcnt vmcnt(0)" ::: "memory")

__global__ __launch_bounds__(512, 2) void k_gemm1_8ph(
    const unsigned short* __restrict__ A,
    const unsigned short* __restrict__ B,
    unsigned short* __restrict__ Crelu) {
  __shared__ __align__(16) char lds[131072];
  const int tid = threadIdx.x;
  const int wid = tid >> 6, l = tid & 63;
  const int wr2 = wid >> 2, wc2 = wid & 3;

  int bid = blockIdx.x;
  int swz = (bid & 7) * 32 + (bid >> 3);   // bijective XCD swizzle (256 = 8*32)
  const int i0 = (swz >> 4) * 256;
  const int c0 = (swz & 15) * 256;

  // fragment-read lane constants (logical col XOR (row&7)<<4 swizzle)
  const int aRow = (wr2 * 64 + (l & 15)) * 128;
  const int bRow = (wc2 * 32 + (l & 15)) * 128;
  const int colKK0 = (((l >> 4) * 16)) ^ ((l & 7) << 4);
  const int colKK1 = ((64 + (l >> 4) * 16)) ^ ((l & 7) << 4);

  // staging lane constants: linear LDS dest, inverse-swizzled global source
  const int srow = tid >> 3;                         // 0..63
  const int scol = (((tid & 7) ^ (srow & 7)) << 4);  // source col chunk ^ row&7
  const char* gA = (const char*)A + (size_t)(i0 + srow) * 8192 + scol;
  const char* gB = (const char*)B + (size_t)(c0 + srow) * 8192 + scol;
  char* ldsW = (char*)lds + wid * 1024;
  const char* ldsR = (const char*)lds;

  f32x4 acc[2][2][4][2];
  #pragma unroll
  for (int qm = 0; qm < 2; ++qm)
    #pragma unroll
    for (int qn = 0; qn < 2; ++qn)
      #pragma unroll
      for (int m = 0; m < 4; ++m)
        #pragma unroll
        for (int n = 0; n < 2; ++n) acc[qm][qn][m][n] = {0.f, 0.f, 0.f, 0.f};

  bf16x8 af[4][2];
  bf16x8 bfr[2][2];

#define STAGE_HALF(GP, OPOFF, KT, QH, BUF) do {                                      \
    const char* _g0 = (GP) + (size_t)((QH) * 128) * 8192 + (size_t)(((KT) & 63)) * 128; \
    char* _l0 = ldsW + (BUF) * 65536 + (OPOFF) + (QH) * 16384;                       \
    __builtin_amdgcn_global_load_lds(                                                \
        (const __attribute__((address_space(1))) void*)_g0,                          \
        (__attribute__((address_space(3))) void*)_l0, 16, 0, 0);                     \
    __builtin_amdgcn_global_load_lds(                                                \
        (const __attribute__((address_space(1))) void*)(_g0 + (size_t)64 * 8192),    \
        (__attribute__((address_space(3))) void*)(_l0 + 8192), 16, 0, 0);            \
  } while (0)

#define STAGE_A(KT, QH, BUF) STAGE_HALF(gA, 0, KT, QH, BUF)
#define STAGE_B(KT, QH, BUF) STAGE_HALF(gB, 32768, KT, QH, BUF)

#define LOAD_A(BUF, QM) do {                                                         \
    _Pragma("unroll")                                                                \
    for (int _m = 0; _m < 4; ++_m) {                                                 \
      const char* _p = ldsR + (BUF) * 65536 + (QM) * 16384 + aRow + _m * 2048;       \
      af[_m][0] = *(const bf16x8*)(_p + colKK0);                                     \
      af[_m][1] = *(const bf16x8*)(_p + colKK1);                                     \
    } } while (0)

#define LOAD_B(BUF, QN) do {                                                         \
    _Pragma("unroll")                                                                \
    for (int _n = 0; _n < 2; ++_n) {                                                 \
      const char* _p = ldsR + (BUF) * 65536 + 32768 + (QN) * 16384 + bRow + _n * 2048; \
      bfr[_n][0] = *(const bf16x8*)(_p + colKK0);                                    \
      bfr[_n][1] = *(const bf16x8*)(_p + colKK1);                                    \
    } } while (0)

#define MFMA16(QM, QN) do {                                                          \
    __builtin_amdgcn_s_setprio(1);                                                   \
    _Pragma("unroll")                                                                \
    for (int _kk = 0; _kk < 2; ++_kk)                                                \
      _Pragma("unroll")                                                              \
      for (int _m = 0; _m < 4; ++_m)                                                 \
        _Pragma("unroll")                                                            \
        for (int _n = 0; _n < 2; ++_n)                                               \
          acc[QM][QN][_m][_n] = __builtin_amdgcn_mfma_f32_16x16x32_bf16(             \
              af[_m][_kk], bfr[_n][_kk], acc[QM][QN][_m][_n], 0, 0, 0);              \
    __builtin_amdgcn_s_setprio(0);                                                   \
  } while (0)

  // Prologue: tile0 (all 4 halves -> buf0), tile1 (A0,B1 -> buf1); allow 2 halves in flight
  STAGE_A(0, 0, 0);
  STAGE_B(0, 1, 0);
  STAGE_A(0, 1, 0);
  STAGE_B(0, 0, 0);
  STAGE_A(1, 0, 1);
  STAGE_B(1, 1, 1);
  VMCNT4();
  SBAR();

  for (int it = 0; it < 32; ++it) {
    const int T = it * 2;
    // ph1: quad(0,0) buf0 | stage A1(T+1)->buf1
    LOAD_A(0, 0); LOAD_B(0, 0);
    STAGE_A(T + 1, 1, 1);
    SBAR(); MFMA16(0, 0); SBAR();
    // ph2: quad(0,1) buf0 | stage B0(T+1)->buf1
    LOAD_B(0, 1);
    STAGE_B(T + 1, 0, 1);
    SBAR(); MFMA16(0, 1); SBAR();
    // ph3: quad(1,1) buf0 | stage A0(T+2)->buf0
    LOAD_A(0, 1);
    STAGE_A(T + 2, 0, 0);
    SBAR(); MFMA16(1, 1); SBAR();
    // ph4: quad(1,0) buf0 | stage B1(T+2)->buf0 | vmcnt(4)
    LOAD_B(0, 0);
    STAGE_B(T + 2, 1, 0);
    VMCNT4();
    SBAR(); MFMA16(1, 0); SBAR();
    // ph5: quad(0,0) buf1 | stage A1(T+2)->buf0
    LOAD_A(1, 0); LOAD_B(1, 0);
    STAGE_A(T + 2, 1, 0);
    SBAR(); MFMA16(0, 0); SBAR();
    // ph6: quad(0,1) buf1 | stage B0(T+2)->buf0
    LOAD_B(1, 1);
    STAGE_B(T + 2, 0, 0);
    SBAR(); MFMA16(0, 1); SBAR();
    // ph7: quad(1,1) buf1 | stage A0(T+3)->buf1
    LOAD_A(1, 1);
    STAGE_A(T + 3, 0, 1);
    SBAR(); MFMA16(1, 1); SBAR();
    // ph8: quad(1,0) buf1 | stage B1(T+3)->buf1 | vmcnt(4)
    LOAD_B(1, 0);
    STAGE_B(T + 3, 1, 1);
    VMCNT4();
    SBAR(); MFMA16(1, 0); SBAR();
  }

  VMCNT0();

  // Epilogue: relu + bf16 store. C/D map: col=lane&15, row=(lane>>4)*4+reg
  const int rb = i0 + wr2 * 64 + (l >> 4) * 4;
  const int cb = c0 + wc2 * 32 + (l & 15);
  #pragma unroll
  for (int qm = 0; qm < 2; ++qm)
    #pragma unroll
    for (int m = 0; m < 4; ++m)
      #pragma unroll
      for (int r = 0; r < 4; ++r) {
        const size_t rowoff = (size_t)(rb + qm * 128 + m * 16 + r) * 4096;
        #pragma unroll
        for (int qn = 0; qn < 2; ++qn)
          #pragma unroll
          for (int n = 0; n < 2; ++n) {
            float v = acc[qm][qn][m][n][r];
            v = v > 0.f ? v : 0.f;
            Crelu[rowoff + cb + qn * 128 + n * 16] = f2bf(v);
          }
      }
}

// ---------------- shared MFMA GEMM core (m97-style, used by gemm2) ----------------
__device__ __forceinline__ void gemm_core(const unsigned short* __restrict__ A,
                                          const unsigned short* __restrict__ B,
                                          int i0, int c0, int k0base, int ksteps,
                                          f32x4 acc[4][4],
                                          unsigned short* Als, unsigned short* Bls) {
  const int tid = threadIdx.x;
  const int w = tid >> 6, l = tid & 63;
  const int srow = (l >> 2);
  const int scol = (l & 3) * 16;   // bytes within 64B row
  for (int kt = 0; kt < ksteps; ++kt) {
    int k0 = k0base + kt * 32;
    #pragma unroll
    for (int q = 0; q < 2; ++q) {
      int r = w * 32 + q * 16 + srow;
      const char* ga = (const char*)(A + (size_t)(i0 + r) * 4096 + k0) + scol;
      __builtin_amdgcn_global_load_lds(
          (const __attribute__((address_space(1))) void*)ga,
          (__attribute__((address_space(3))) void*)((char*)Als + w * 2048 + q * 1024),
          16, 0, 0);
      const char* gb = (const char*)(B + (size_t)(c0 + r) * 4096 + k0) + scol;
      __builtin_amdgcn_global_load_lds(
          (const __attribute__((address_space(1))) void*)gb,
          (__attribute__((address_space(3))) void*)((char*)Bls + w * 2048 + q * 1024),
          16, 0, 0);
    }
    __syncthreads();
    const int wr = w >> 1, wc = w & 1;
    bf16x8 af[4], bff[4];
    #pragma unroll
    for (int m = 0; m < 4; ++m)
      af[m] = *(const bf16x8*)(Als + (wr * 64 + m * 16 + (l & 15)) * 32 + (l >> 4) * 8);
    #pragma unroll
    for (int n = 0; n < 4; ++n)
      bff[n] = *(const bf16x8*)(Bls + (wc * 64 + n * 16 + (l & 15)) * 32 + (l >> 4) * 8);
    #pragma unroll
    for (int m = 0; m < 4; ++m)
      #pragma unroll
      for (int n = 0; n < 4; ++n)
        acc[m][n] = __builtin_amdgcn_mfma_f32_16x16x32_bf16(af[m], bff[n], acc[m][n], 0, 0, 0);
    __syncthreads();
  }
}

// ---------------- support2: B2t[s*2+o][i] = relu_h . W2 + b2 (bf16) ----------------
__global__ __launch_bounds__(256) void k_support2(const unsigned short* __restrict__ Hr,
                                                 const float* __restrict__ W2,
                                                 const float* __restrict__ b2,
                                                 unsigned short* __restrict__ B2t) {
  __shared__ float w2l[128];
  __shared__ float b2l[2];
  int s = blockIdx.x >> 4, ib = blockIdx.x & 15;
  int tid = threadIdx.x;
  if (tid < 128) w2l[tid] = W2[tid];
  if (tid < 2) b2l[tid] = b2[tid];
  __syncthreads();
  int i = ib * 256 + tid;
  const u16x8* hp = (const u16x8*)(Hr + (size_t)i * 4096 + s * 64);
  float acc0 = b2l[0], acc1 = b2l[1];
  #pragma unroll
  for (int q = 0; q < 8; ++q) {
    u16x8 hv = hp[q];
    #pragma unroll
    for (int e = 0; e < 8; ++e) {
      float f = bf2f((unsigned short)hv[e]);
      acc0 += f * w2l[(q * 8 + e) * 2];
      acc1 += f * w2l[(q * 8 + e) * 2 + 1];
    }
  }
  B2t[(size_t)(s * 2 + 0) * 4096 + i] = f2bf(acc0);
  B2t[(size_t)(s * 2 + 1) * 4096 + i] = f2bf(acc1);
}

// ---------------- GEMM2 split-K: Gp[ks][i][c2] partial f32 ----------------
__global__ __launch_bounds__(256) void k_gemm2(const unsigned short* __restrict__ A,
                                               const unsigned short* __restrict__ B,
                                               float* __restrict__ Gp) {
  __shared__ unsigned short Als[128 * 32], Bls[128 * 32];
  int id = blockIdx.x;
  int bi = id & 31, ks = id >> 5;
  int i0 = bi * 128;
  f32x4 acc[4][4];
  #pragma unroll
  for (int m = 0; m < 4; ++m)
    #pragma unroll
    for (int n = 0; n < 4; ++n) acc[m][n] = {0.f, 0.f, 0.f, 0.f};
  gemm_core(A, B, i0, 0, ks * 512, 16, acc, Als, Bls);
  float* outp = Gp + (size_t)ks * 4096 * 128;
  int l = threadIdx.x & 63, w = threadIdx.x >> 6;
  int wr = w >> 1, wc = w & 1;
  int rbase = i0 + wr * 64 + (l >> 4) * 4;
  int cbase = wc * 64 + (l & 15);
  #pragma unroll
  for (int m = 0; m < 4; ++m)
    #pragma unroll
    for (int n = 0; n < 4; ++n)
      #pragma unroll
      for (int r = 0; r < 4; ++r)
        outp[(size_t)(rbase + m * 16 + r) * 128 + cbase + n * 16] = acc[m][n][r];
}

// ---------------- reduce split-K + log_softmax -> R[s][i*2+o] f32 ----------------
__global__ __launch_bounds__(256) void k_lsm(const float* __restrict__ Gp,
                                             float* __restrict__ Rm) {
  __shared__ float Gacc[32][130];
  int i0 = blockIdx.x * 32;
  int tid = threadIdx.x;
  float4 v[4];
  #pragma unroll
  for (int i = 0; i < 4; ++i) v[i] = {0.f, 0.f, 0.f, 0.f};
  for (int ks = 0; ks < 8; ++ks) {
    const float4* gp4 = ((const float4*)Gp) + (size_t)ks * 131072 + (size_t)i0 * 32;
    #pragma unroll
    for (int i = 0; i < 4; ++i) {
      float4 t = gp4[tid + i * 256];
      v[i].x += t.x; v[i].y += t.y; v[i].z += t.z; v[i].w += t.w;
    }
  }
  #pragma unroll
  for (int i = 0; i < 4; ++i) {
    int f4i = tid + i * 256, row = f4i >> 5, c = (f4i & 31) * 4;
    Gacc[row][c] = v[i].x; Gacc[row][c + 1] = v[i].y;
    Gacc[row][c + 2] = v[i].z; Gacc[row][c + 3] = v[i].w;
  }
  __syncthreads();
  #pragma unroll
  for (int j = 0; j < 8; ++j) {
    int p = j * 256 + tid;
    int ii = p & 31, s = p >> 5;
    float g0 = Gacc[ii][s * 2], g1 = Gacc[ii][s * 2 + 1];
    float m = fmaxf(g0, g1);
    float lse = m + logf(expf(g0 - m) + expf(g1 - m));
    float2 o_; o_.x = g0 - lse; o_.y = g1 - lse;
    *((float2*)(Rm + (size_t)s * 8192 + (size_t)(i0 + ii) * 2)) = o_;
  }
}

// ---------------- gi0 partial: part[ks][t][g] = R[t] . Wih0[g] over c-range ----------------
__global__ __launch_bounds__(256) void k_gi0(const float* __restrict__ Rm,
                                             const float* __restrict__ Wih0,
                                             float* __restrict__ part) {
  __shared__ float4 Wl[4 * 128];
  int gb = blockIdx.x % 48, ks = blockIdx.x / 48;
  int c0 = ks * 512;
  int tid = threadIdx.x;
  #pragma unroll
  for (int i = 0; i < 2; ++i) {
    int idx = tid + i * 256;
    int g = idx >> 7, c4 = idx & 127;
    Wl[g * 128 + c4] = ((const float4*)(Wih0 + (size_t)(gb * 4 + g) * 8192 + c0))[c4];
  }
  __syncthreads();
  int w = tid >> 6, lane = tid & 63;
  for (int pass = 0; pass < 16; ++pass) {
    int t = pass * 4 + w;
    float a0 = 0.f, a1 = 0.f, a2 = 0.f, a3 = 0.f;
    const float4* rg = (const float4*)(Rm + (size_t)t * 8192 + c0);
    #pragma unroll
    for (int i = 0; i < 2; ++i) {
      int c4 = i * 64 + lane;
      float4 r4 = rg[c4];
      float4 w0 = Wl[c4], w1 = Wl[128 + c4], w2 = Wl[256 + c4], w3 = Wl[384 + c4];
      a0 += r4.x * w0.x + r4.y * w0.y + r4.z * w0.z + r4.w * w0.w;
      a1 += r4.x * w1.x + r4.y * w1.y + r4.z * w1.z + r4.w * w1.w;
      a2 += r4.x * w2.x + r4.y * w2.y + r4.z * w2.z + r4.w * w2.w;
      a3 += r4.x * w3.x + r4.y * w3.y + r4.z * w3.z + r4.w * w3.w;
    }
    #pragma unroll
    for (int off = 1; off < 64; off <<= 1) {
      a0 += __shfl_xor(a0, off);
      a1 += __shfl_xor(a1, off);
      a2 += __shfl_xor(a2, off);
      a3 += __shfl_xor(a3, off);
    }
    if (lane == 0) {
      float4 o_; o_.x = a0; o_.y = a1; o_.z = a2; o_.w = a3;
      *((float4*)(part + ((size_t)ks * 64 + t) * 192 + gb * 4)) = o_;
    }
  }
}

__global__ __launch_bounds__(256) void k_gi0red(const float* __restrict__ part,
                                                const float* __restrict__ bih0,
                                                float* __restrict__ gi0) {
  int idx = blockIdx.x * 256 + threadIdx.x;
  if (idx < 12288) {
    float s_ = bih0[idx % 192];
    for (int ks = 0; ks < 16; ++ks) s_ += part[ks * 12288 + idx];
    gi0[idx] = s_;
  }
}

// ---------------- fused 2-layer GRU, batch 1, weights in VGPRs ----------------
__global__ __launch_bounds__(192) void k_gru(const float* __restrict__ gi0,
                                             const float* __restrict__ Whh0,
                                             const float* __restrict__ bhh0,
                                             const float* __restrict__ Wih1,
                                             const float* __restrict__ Whh1,
                                             const float* __restrict__ bih1,
                                             const float* __restrict__ bhh1,
                                             float* __restrict__ out) {
  __shared__ float h0s[64], h1s[64], ys0s[64], gA[192], uA[192], vA[192];
  int g = threadIdx.x;
  float w0[64], wi1[64], wh1[64];
  #pragma unroll
  for (int k = 0; k < 16; ++k) {
    float4 t0 = ((const float4*)(Whh0 + (size_t)g * 64))[k];
    float4 t1 = ((const float4*)(Wih1 + (size_t)g * 64))[k];
    float4 t2 = ((const float4*)(Whh1 + (size_t)g * 64))[k];
    w0[k * 4] = t0.x; w0[k * 4 + 1] = t0.y; w0[k * 4 + 2] = t0.z; w0[k * 4 + 3] = t0.w;
    wi1[k * 4] = t1.x; wi1[k * 4 + 1] = t1.y; wi1[k * 4 + 2] = t1.z; wi1[k * 4 + 3] = t1.w;
    wh1[k * 4] = t2.x; wh1[k * 4 + 1] = t2.y; wh1[k * 4 + 2] = t2.z; wh1[k * 4 + 3] = t2.w;
  }
  float bh0 = bhh0[g], bi1 = bih1[g], bh1 = bhh1[g];
  if (g < 64) { h0s[g] = 0.f; h1s[g] = 0.f; }
  __syncthreads();
  for (int t = 0; t < 64; ++t) {
    float a0 = 0.f, a1 = 0.f, a2 = 0.f, a3 = 0.f;
    #pragma unroll
    for (int k = 0; k < 16; ++k) {
      float4 h4 = *(const float4*)&h0s[k * 4];
      a0 += w0[k * 4] * h4.x; a1 += w0[k * 4 + 1] * h4.y;
      a2 += w0[k * 4 + 2] * h4.z; a3 += w0[k * 4 + 3] * h4.w;
    }
    float gh = (a0 + a1) + (a2 + a3) + bh0;
    float giv = gi0[t * 192 + g];
    gA[g] = (g < 128) ? (giv + gh) : gh;
    __syncthreads();
    if (g < 64) {
      float r = 1.f / (1.f + expf(-gA[g]));
      float z = 1.f / (1.f + expf(-gA[g + 64]));
      float inn = gi0[t * 192 + 128 + g];
      float n = tanhf(inn + r * gA[g + 128]);
      float hnew = (1.f - z) * n + z * h0s[g];
      h0s[g] = hnew; ys0s[g] = hnew;
    }
    __syncthreads();
    float b0 = 0.f, b1_ = 0.f, b2_ = 0.f, b3 = 0.f;
    float c0 = 0.f, c1 = 0.f, c2 = 0.f, c3 = 0.f;
    #pragma unroll
    for (int k = 0; k < 16; ++k) {
      float4 y4 = *(const float4*)&ys0s[k * 4];
      float4 h4 = *(const float4*)&h1s[k * 4];
      b0 += wi1[k * 4] * y4.x; b1_ += wi1[k * 4 + 1] * y4.y;
      b2_ += wi1[k * 4 + 2] * y4.z; b3 += wi1[k * 4 + 3] * y4.w;
      c0 += wh1[k * 4] * h4.x; c1 += wh1[k * 4 + 1] * h4.y;
      c2 += wh1[k * 4 + 2] * h4.z; c3 += wh1[k * 4 + 3] * h4.w;
    }
    uA[g] = (b0 + b1_) + (b2_ + b3) + bi1;
    vA[g] = (c0 + c1) + (c2 + c3) + bh1;
    __syncthreads();
    if (g < 64) {
      float r = 1.f / (1.f + expf(-(uA[g] + vA[g])));
      float z = 1.f / (1.f + expf(-(uA[g + 64] + vA[g + 64])));
      float n = tanhf(uA[g + 128] + r * vA[g + 128]);
      float hnew = (1.f - z) * n + z * h1s[g];
      h1s[g] = hnew;
      out[t * 64 + g] = hnew;
    }
    __syncthreads();
  }
  if (g < 64) { out[4096 + g] = h0s[g]; out[4096 + 64 + g] = h1s[g]; }
}

extern "C" void kernel_launch(void* const* d_in, const int* in_sizes, int n_in,
                              void* d_out, int out_size, void* d_ws, size_t ws_size,
                              hipStream_t stream) {
  const float* x    = (const float*)d_in[0];
  const float* adj  = (const float*)d_in[1];
  const float* W1   = (const float*)d_in[2];
  const float* b1   = (const float*)d_in[3];
  const float* W2   = (const float*)d_in[4];
  const float* b2   = (const float*)d_in[5];
  const float* Wih0 = (const float*)d_in[6];
  const float* Whh0 = (const float*)d_in[7];
  const float* bih0 = (const float*)d_in[8];
  const float* bhh0 = (const float*)d_in[9];
  const float* Wih1 = (const float*)d_in[10];
  const float* Whh1 = (const float*)d_in[11];
  const float* bih1 = (const float*)d_in[12];
  const float* bhh1 = (const float*)d_in[13];
  float* out = (float*)d_out;

  char* ws = (char*)d_ws;
  // [0,32M): adjb ; [32M,64M): Bt, later reused for Gp/Rm/part/gi0/B2t ; [64M,96M): Hrelu
  unsigned short* adjb = (unsigned short*)ws;
  unsigned short* Bt   = (unsigned short*)(ws + 33554432);
  unsigned short* Hr   = (unsigned short*)(ws + 67108864);
  float* Gp   = (float*)(ws + 33554432);              // 16MB (Bt dead after gemm1)
  float* Rm   = (float*)(ws + 50331648);              // 2MB
  float* part = (float*)(ws + 52428800);              // 768KB
  float* gi0  = (float*)(ws + 53215232);              // 48KB
  unsigned short* B2t = (unsigned short*)(ws + 53264384); // 1MB

  k_cvt<<<4096, 256, 0, stream>>>(adj, adjb, 4194304);
  k_support<<<4096, 256, 0, stream>>>(x, W1, b1, Bt);
  k_gemm1_8ph<<<256, 512, 0, stream>>>(adjb, Bt, Hr);
  k_support2<<<1024, 256, 0, stream>>>(Hr, W2, b2, B2t);
  k_gemm2<<<256, 256, 0, stream>>>(adjb, B2t, Gp);
  k_lsm<<<128, 256, 0, stream>>>(Gp, Rm);
  k_gi0<<<768, 256, 0, stream>>>(Rm, Wih0, part);
  k_gi0red<<<48, 256, 0, stream>>>(part, bih0, gi0);
  k_gru<<<1, 192, 0, stream>>>(gi0, Whh0, bhh0, Wih1, Whh1, bih1, bhh1, out);
}

// Round 3
// 336.434 us; speedup vs baseline: 1.2479x; 1.0173x over previous
//
#include <hip/hip_runtime.h>
#include <stdint.h>

#define SS 64
#define NN 4096
#define FF 32
#define HH 64
#define OO 2
#define G3 192

typedef float f32x4 __attribute__((ext_vector_type(4)));
typedef short bf16x8 __attribute__((ext_vector_type(8)));
typedef unsigned short u16x8 __attribute__((ext_vector_type(8)));

__device__ __forceinline__ unsigned short f2bf(float f) {
  union { float f; uint32_t u; } v; v.f = f;
  uint32_t u = v.u;
  uint32_t r = (u + 0x7FFFu + ((u >> 16) & 1u)) >> 16;
  return (unsigned short)r;
}
__device__ __forceinline__ float bf2f(unsigned short s) {
  union { uint32_t u; float f; } v; v.u = ((uint32_t)s) << 16;
  return v.f;
}

// ---------------- fused: adj f32->bf16 (blocks 0..4095) + support (blocks 4096..8191) ----------------
__global__ __launch_bounds__(256) void k_prep(const float* __restrict__ adj,
                                              unsigned short* __restrict__ adjb,
                                              const float* __restrict__ x,
                                              const float* __restrict__ W1,
                                              const float* __restrict__ b1,
                                              unsigned short* __restrict__ Bt) {
  int tid = threadIdx.x;
  if (blockIdx.x < 4096) {
    int id = blockIdx.x * 256 + tid;
    #pragma unroll
    for (int it = 0; it < 4; ++it) {
      int i = id + it * 1048576;
      float4 v = ((const float4*)adj)[i];
      ushort4 r;
      r.x = f2bf(v.x); r.y = f2bf(v.y); r.z = f2bf(v.z); r.w = f2bf(v.w);
      ((ushort4*)adjb)[i] = r;
    }
    return;
  }
  __shared__ float xl[64][33];
  __shared__ float w1l[32 * 64];
  __shared__ float b1l[64];
  int bs = blockIdx.x - 4096;
  int s = bs >> 6, jb = (bs & 63) << 6;
  const float4* xg = (const float4*)(x + ((size_t)s * NN + jb) * FF);
  #pragma unroll
  for (int i = 0; i < 2; ++i) {
    int idx = tid + i * 256;
    float4 v = xg[idx];
    int j = idx >> 3, f = (idx & 7) << 2;
    xl[j][f] = v.x; xl[j][f + 1] = v.y; xl[j][f + 2] = v.z; xl[j][f + 3] = v.w;
  }
  #pragma unroll
  for (int i = 0; i < 2; ++i) {
    int idx = tid + i * 256;
    float4 v = ((const float4*)W1)[idx];
    w1l[idx * 4] = v.x; w1l[idx * 4 + 1] = v.y; w1l[idx * 4 + 2] = v.z; w1l[idx * 4 + 3] = v.w;
  }
  if (tid < 64) b1l[tid] = b1[tid];
  __syncthreads();
  int jj = tid & 63, hq = tid >> 6;
  unsigned short* outb = Bt + (size_t)(s * HH) * NN + jb + jj;
  #pragma unroll
  for (int hh = 0; hh < 16; ++hh) {
    int h = hq * 16 + hh;
    float acc = b1l[h];
    #pragma unroll
    for (int f = 0; f < FF; ++f) acc += xl[jj][f] * w1l[f * 64 + h];
    outb[(size_t)h * NN] = f2bf(acc);
  }
}

// =====================================================================
// GEMM1: 256x256 tile, BK=64, 8 waves, 8-phase, uniform 2-load staging,
// vmcnt(6) at ph4/ph8 (3 stage-groups in flight). Epilogue fuses
// support2: B2t[s*2+o][i] = f2bf(b2[o] + sum_h relu(C[i][s*64+h])*W2[h][o])
// =====================================================================
#define SBAR()   asm volatile("s_barrier" ::: "memory")
#define VMCNT6() asm volatile("s_waitcnt vmcnt(6)" ::: "memory")
#define VMCNT0() asm volatile("s_waitcnt vmcnt(0)" ::: "memory")

__global__ __launch_bounds__(512, 2) void k_gemm1_8ph(
    const unsigned short* __restrict__ A,
    const unsigned short* __restrict__ B,
    const float* __restrict__ W2,
    const float* __restrict__ b2,
    unsigned short* __restrict__ B2t) {
  __shared__ __align__(16) char lds[131072];
  const int tid = threadIdx.x;
  const int wid = tid >> 6, l = tid & 63;
  const int wr2 = wid >> 2, wc2 = wid & 3;

  int bid = blockIdx.x;
  int swz = (bid & 7) * 32 + (bid >> 3);   // bijective XCD swizzle (256 = 8*32)
  const int i0 = (swz >> 4) * 256;
  const int c0 = (swz & 15) * 256;

  // fragment-read lane constants (logical col XOR (row&7)<<4 swizzle)
  const int aRow = (wr2 * 64 + (l & 15)) * 128;
  const int bRow = (wc2 * 32 + (l & 15)) * 128;
  const int colKK0 = (((l >> 4) * 16)) ^ ((l & 7) << 4);
  const int colKK1 = ((64 + (l >> 4) * 16)) ^ ((l & 7) << 4);

  // staging lane constants: linear LDS dest, inverse-swizzled global source
  const int srow = tid >> 3;                         // 0..63
  const int scol = (((tid & 7) ^ (srow & 7)) << 4);  // source col chunk ^ row&7
  const char* gA = (const char*)A + (size_t)(i0 + srow) * 8192 + scol;
  const char* gB = (const char*)B + (size_t)(c0 + srow) * 8192 + scol;
  char* ldsW = (char*)lds + wid * 1024;
  const char* ldsR = (const char*)lds;

  f32x4 acc[2][2][4][2];
  #pragma unroll
  for (int qm = 0; qm < 2; ++qm)
    #pragma unroll
    for (int qn = 0; qn < 2; ++qn)
      #pragma unroll
      for (int m = 0; m < 4; ++m)
        #pragma unroll
        for (int n = 0; n < 2; ++n) acc[qm][qn][m][n] = {0.f, 0.f, 0.f, 0.f};

  bf16x8 af[4][2];
  bf16x8 bfr[2][2];

#define STAGE_HALF(GP, OPOFF, KT, QH, BUF) do {                                      \
    const char* _g0 = (GP) + (size_t)((QH) * 128) * 8192 + (size_t)(((KT) & 63)) * 128; \
    char* _l0 = ldsW + (BUF) * 65536 + (OPOFF) + (QH) * 16384;                       \
    __builtin_amdgcn_global_load_lds(                                                \
        (const __attribute__((address_space(1))) void*)_g0,                          \
        (__attribute__((address_space(3))) void*)_l0, 16, 0, 0);                     \
    __builtin_amdgcn_global_load_lds(                                                \
        (const __attribute__((address_space(1))) void*)(_g0 + (size_t)64 * 8192),    \
        (__attribute__((address_space(3))) void*)(_l0 + 8192), 16, 0, 0);            \
  } while (0)

#define STAGE_A(KT, QH, BUF) STAGE_HALF(gA, 0, KT, QH, BUF)
#define STAGE_B(KT, QH, BUF) STAGE_HALF(gB, 32768, KT, QH, BUF)

#define LOAD_A(BUF, QM) do {                                                         \
    _Pragma("unroll")                                                                \
    for (int _m = 0; _m < 4; ++_m) {                                                 \
      const char* _p = ldsR + (BUF) * 65536 + (QM) * 16384 + aRow + _m * 2048;       \
      af[_m][0] = *(const bf16x8*)(_p + colKK0);                                     \
      af[_m][1] = *(const bf16x8*)(_p + colKK1);                                     \
    } } while (0)

#define LOAD_B(BUF, QN) do {                                                         \
    _Pragma("unroll")                                                                \
    for (int _n = 0; _n < 2; ++_n) {                                                 \
      const char* _p = ldsR + (BUF) * 65536 + 32768 + (QN) * 16384 + bRow + _n * 2048; \
      bfr[_n][0] = *(const bf16x8*)(_p + colKK0);                                    \
      bfr[_n][1] = *(const bf16x8*)(_p + colKK1);                                    \
    } } while (0)

#define MFMA16(QM, QN) do {                                                          \
    __builtin_amdgcn_s_setprio(1);                                                   \
    _Pragma("unroll")                                                                \
    for (int _kk = 0; _kk < 2; ++_kk)                                                \
      _Pragma("unroll")                                                              \
      for (int _m = 0; _m < 4; ++_m)                                                 \
        _Pragma("unroll")                                                            \
        for (int _n = 0; _n < 2; ++_n)                                               \
          acc[QM][QN][_m][_n] = __builtin_amdgcn_mfma_f32_16x16x32_bf16(             \
              af[_m][_kk], bfr[_n][_kk], acc[QM][QN][_m][_n], 0, 0, 0);              \
    __builtin_amdgcn_s_setprio(0);                                                   \
  } while (0)

  // Prologue: tile0 complete (8 loads) + A0,B1,A1 of tile1 (6 loads); vmcnt(6)
  // forces tile0 done, leaves tile1's 6 in flight (steady state).
  STAGE_A(0, 0, 0); STAGE_A(0, 1, 0); STAGE_B(0, 0, 0); STAGE_B(0, 1, 0);
  STAGE_A(1, 0, 1); STAGE_B(1, 1, 1); STAGE_A(1, 1, 1);
  VMCNT6();
  SBAR();

  // Region free-list: buf0 A0@ph1 B1@ph2 A1@ph3 B0@ph4 ; buf1 A0@ph5 B1@ph6 A1@ph7 B0@ph8.
  // Each phase stages the region freed in the previous phase (2 loads/phase).
  for (int it = 0; it < 32; ++it) {
    const int T = it * 2;
    // ph1: quad(0,0) buf0 | stage B0(T+1)->buf1
    LOAD_A(0, 0); LOAD_B(0, 0);
    STAGE_B(T + 1, 0, 1);
    SBAR(); MFMA16(0, 0); SBAR();
    // ph2: quad(0,1) buf0 | stage A0(T+2)->buf0
    LOAD_B(0, 1);
    STAGE_A(T + 2, 0, 0);
    SBAR(); MFMA16(0, 1); SBAR();
    // ph3: quad(1,1) buf0 | stage B1(T+2)->buf0
    LOAD_A(0, 1);
    STAGE_B(T + 2, 1, 0);
    SBAR(); MFMA16(1, 1); SBAR();
    // ph4: quad(1,0) buf0 | stage A1(T+2)->buf0 | vmcnt(6): tile T+1 complete
    LOAD_B(0, 0);
    STAGE_A(T + 2, 1, 0);
    VMCNT6();
    SBAR(); MFMA16(1, 0); SBAR();
    // ph5: quad(0,0) buf1 | stage B0(T+2)->buf0
    LOAD_A(1, 0); LOAD_B(1, 0);
    STAGE_B(T + 2, 0, 0);
    SBAR(); MFMA16(0, 0); SBAR();
    // ph6: quad(0,1) buf1 | stage A0(T+3)->buf1
    LOAD_B(1, 1);
    STAGE_A(T + 3, 0, 1);
    SBAR(); MFMA16(0, 1); SBAR();
    // ph7: quad(1,1) buf1 | stage B1(T+3)->buf1
    LOAD_A(1, 1);
    STAGE_B(T + 3, 1, 1);
    SBAR(); MFMA16(1, 1); SBAR();
    // ph8: quad(1,0) buf1 | stage A1(T+3)->buf1 | vmcnt(6): tile T+2 complete
    LOAD_B(1, 0);
    STAGE_A(T + 3, 1, 1);
    VMCNT6();
    SBAR(); MFMA16(1, 0); SBAR();
  }

  VMCNT0();
  __syncthreads();   // drain; LDS reusable for reduction

  // ---- fused support2 epilogue ----
  // thread's cols: cc = qn*128 + wc2*32 + n*16 + (l&15) -> sg = qn*2+(wc2>>1),
  // h = (wc2&1)*32 + n*16 + (l&15). Rows: lr = qm*128+wr2*64+m*16+(l>>4)*4+r.
  float* part = (float*)lds;                 // [8][2048] f32 = 64 KiB
  const int wc1 = wc2 & 1;
  const int l15 = l & 15;
  float w2r[2][2];
  #pragma unroll
  for (int n = 0; n < 2; ++n)
    #pragma unroll
    for (int o = 0; o < 2; ++o)
      w2r[n][o] = W2[(wc1 * 32 + n * 16 + l15) * 2 + o];

  const int pidx = wc1 * 4 + (l15 >> 2);
  const int gbase = (l >> 4) * 4;
  #pragma unroll
  for (int qm = 0; qm < 2; ++qm)
    #pragma unroll
    for (int m = 0; m < 4; ++m)
      #pragma unroll
      for (int r = 0; r < 4; ++r) {
        const int lr = qm * 128 + wr2 * 64 + m * 16 + gbase + r;
        #pragma unroll
        for (int qn = 0; qn < 2; ++qn) {
          float a0 = acc[qm][qn][m][0][r]; a0 = a0 > 0.f ? a0 : 0.f;
          float a1 = acc[qm][qn][m][1][r]; a1 = a1 > 0.f ? a1 : 0.f;
          const int sg = qn * 2 + (wc2 >> 1);
          #pragma unroll
          for (int o = 0; o < 2; ++o) {
            float v = a0 * w2r[0][o] + a1 * w2r[1][o];
            v += __shfl_xor(v, 1);
            v += __shfl_xor(v, 2);
            if ((l & 3) == 0)
              part[pidx * 2048 + (sg * 2 + o) * 256 + lr] = v;
          }
        }
      }
  __syncthreads();
  {
    const int so = tid >> 6;          // sg*2+o
    const int o = so & 1, sg = so >> 1;
    const int ib = (tid & 63) * 4;
    const float bo = b2[o];
    unsigned short tmp[4];
    #pragma unroll
    for (int k = 0; k < 4; ++k) {
      const int v = so * 256 + ib + k;
      float s_ = 0.f;
      #pragma unroll
      for (int p = 0; p < 8; ++p) s_ += part[p * 2048 + v];
      tmp[k] = f2bf(s_ + bo);
    }
    ushort4 outv; outv.x = tmp[0]; outv.y = tmp[1]; outv.z = tmp[2]; outv.w = tmp[3];
    *(ushort4*)(B2t + (size_t)(((c0 >> 6) + sg) * 2 + o) * 4096 + i0 + ib) = outv;
  }
}

// ---------------- shared MFMA GEMM core (m97-style, used by gemm2) ----------------
__device__ __forceinline__ void gemm_core(const unsigned short* __restrict__ A,
                                          const unsigned short* __restrict__ B,
                                          int i0, int c0, int k0base, int ksteps,
                                          f32x4 acc[4][4],
                                          unsigned short* Als, unsigned short* Bls) {
  const int tid = threadIdx.x;
  const int w = tid >> 6, l = tid & 63;
  const int srow = (l >> 2);
  const int scol = (l & 3) * 16;   // bytes within 64B row
  for (int kt = 0; kt < ksteps; ++kt) {
    int k0 = k0base + kt * 32;
    #pragma unroll
    for (int q = 0; q < 2; ++q) {
      int r = w * 32 + q * 16 + srow;
      const char* ga = (const char*)(A + (size_t)(i0 + r) * 4096 + k0) + scol;
      __builtin_amdgcn_global_load_lds(
          (const __attribute__((address_space(1))) void*)ga,
          (__attribute__((address_space(3))) void*)((char*)Als + w * 2048 + q * 1024),
          16, 0, 0);
      const char* gb = (const char*)(B + (size_t)(c0 + r) * 4096 + k0) + scol;
      __builtin_amdgcn_global_load_lds(
          (const __attribute__((address_space(1))) void*)gb,
          (__attribute__((address_space(3))) void*)((char*)Bls + w * 2048 + q * 1024),
          16, 0, 0);
    }
    __syncthreads();
    const int wr = w >> 1, wc = w & 1;
    bf16x8 af[4], bff[4];
    #pragma unroll
    for (int m = 0; m < 4; ++m)
      af[m] = *(const bf16x8*)(Als + (wr * 64 + m * 16 + (l & 15)) * 32 + (l >> 4) * 8);
    #pragma unroll
    for (int n = 0; n < 4; ++n)
      bff[n] = *(const bf16x8*)(Bls + (wc * 64 + n * 16 + (l & 15)) * 32 + (l >> 4) * 8);
    #pragma unroll
    for (int m = 0; m < 4; ++m)
      #pragma unroll
      for (int n = 0; n < 4; ++n)
        acc[m][n] = __builtin_amdgcn_mfma_f32_16x16x32_bf16(af[m], bff[n], acc[m][n], 0, 0, 0);
    __syncthreads();
  }
}

// ---------------- GEMM2 split-K: Gp[ks][i][c2] partial f32 ----------------
__global__ __launch_bounds__(256) void k_gemm2(const unsigned short* __restrict__ A,
                                               const unsigned short* __restrict__ B,
                                               float* __restrict__ Gp) {
  __shared__ unsigned short Als[128 * 32], Bls[128 * 32];
  int id = blockIdx.x;
  int bi = id & 31, ks = id >> 5;
  int i0 = bi * 128;
  f32x4 acc[4][4];
  #pragma unroll
  for (int m = 0; m < 4; ++m)
    #pragma unroll
    for (int n = 0; n < 4; ++n) acc[m][n] = {0.f, 0.f, 0.f, 0.f};
  gemm_core(A, B, i0, 0, ks * 512, 16, acc, Als, Bls);
  float* outp = Gp + (size_t)ks * 4096 * 128;
  int l = threadIdx.x & 63, w = threadIdx.x >> 6;
  int wr = w >> 1, wc = w & 1;
  int rbase = i0 + wr * 64 + (l >> 4) * 4;
  int cbase = wc * 64 + (l & 15);
  #pragma unroll
  for (int m = 0; m < 4; ++m)
    #pragma unroll
    for (int n = 0; n < 4; ++n)
      #pragma unroll
      for (int r = 0; r < 4; ++r)
        outp[(size_t)(rbase + m * 16 + r) * 128 + cbase + n * 16] = acc[m][n][r];
}

// ---------------- reduce split-K + log_softmax -> R[s][i*2+o] f32 ----------------
__global__ __launch_bounds__(256) void k_lsm(const float* __restrict__ Gp,
                                             float* __restrict__ Rm) {
  __shared__ float Gacc[32][130];
  int i0 = blockIdx.x * 32;
  int tid = threadIdx.x;
  float4 v[4];
  #pragma unroll
  for (int i = 0; i < 4; ++i) v[i] = {0.f, 0.f, 0.f, 0.f};
  for (int ks = 0; ks < 8; ++ks) {
    const float4* gp4 = ((const float4*)Gp) + (size_t)ks * 131072 + (size_t)i0 * 32;
    #pragma unroll
    for (int i = 0; i < 4; ++i) {
      float4 t = gp4[tid + i * 256];
      v[i].x += t.x; v[i].y += t.y; v[i].z += t.z; v[i].w += t.w;
    }
  }
  #pragma unroll
  for (int i = 0; i < 4; ++i) {
    int f4i = tid + i * 256, row = f4i >> 5, c = (f4i & 31) * 4;
    Gacc[row][c] = v[i].x; Gacc[row][c + 1] = v[i].y;
    Gacc[row][c + 2] = v[i].z; Gacc[row][c + 3] = v[i].w;
  }
  __syncthreads();
  #pragma unroll
  for (int j = 0; j < 8; ++j) {
    int p = j * 256 + tid;
    int ii = p & 31, s = p >> 5;
    float g0 = Gacc[ii][s * 2], g1 = Gacc[ii][s * 2 + 1];
    float m = fmaxf(g0, g1);
    float lse = m + logf(expf(g0 - m) + expf(g1 - m));
    float2 o_; o_.x = g0 - lse; o_.y = g1 - lse;
    *((float2*)(Rm + (size_t)s * 8192 + (size_t)(i0 + ii) * 2)) = o_;
  }
}

// ---------------- gi0 partial: part[ks][t][g] = R[t] . Wih0[g] over c-range ----------------
__global__ __launch_bounds__(256) void k_gi0(const float* __restrict__ Rm,
                                             const float* __restrict__ Wih0,
                                             float* __restrict__ part) {
  __shared__ float4 Wl[4 * 128];
  int gb = blockIdx.x % 48, ks = blockIdx.x / 48;
  int c0 = ks * 512;
  int tid = threadIdx.x;
  #pragma unroll
  for (int i = 0; i < 2; ++i) {
    int idx = tid + i * 256;
    int g = idx >> 7, c4 = idx & 127;
    Wl[g * 128 + c4] = ((const float4*)(Wih0 + (size_t)(gb * 4 + g) * 8192 + c0))[c4];
  }
  __syncthreads();
  int w = tid >> 6, lane = tid & 63;
  for (int pass = 0; pass < 16; ++pass) {
    int t = pass * 4 + w;
    float a0 = 0.f, a1 = 0.f, a2 = 0.f, a3 = 0.f;
    const float4* rg = (const float4*)(Rm + (size_t)t * 8192 + c0);
    #pragma unroll
    for (int i = 0; i < 2; ++i) {
      int c4 = i * 64 + lane;
      float4 r4 = rg[c4];
      float4 w0 = Wl[c4], w1 = Wl[128 + c4], w2 = Wl[256 + c4], w3 = Wl[384 + c4];
      a0 += r4.x * w0.x + r4.y * w0.y + r4.z * w0.z + r4.w * w0.w;
      a1 += r4.x * w1.x + r4.y * w1.y + r4.z * w1.z + r4.w * w1.w;
      a2 += r4.x * w2.x + r4.y * w2.y + r4.z * w2.z + r4.w * w2.w;
      a3 += r4.x * w3.x + r4.y * w3.y + r4.z * w3.z + r4.w * w3.w;
    }
    #pragma unroll
    for (int off = 1; off < 64; off <<= 1) {
      a0 += __shfl_xor(a0, off);
      a1 += __shfl_xor(a1, off);
      a2 += __shfl_xor(a2, off);
      a3 += __shfl_xor(a3, off);
    }
    if (lane == 0) {
      float4 o_; o_.x = a0; o_.y = a1; o_.z = a2; o_.w = a3;
      *((float4*)(part + ((size_t)ks * 64 + t) * 192 + gb * 4)) = o_;
    }
  }
}

__global__ __launch_bounds__(256) void k_gi0red(const float* __restrict__ part,
                                                const float* __restrict__ bih0,
                                                float* __restrict__ gi0) {
  int idx = blockIdx.x * 256 + threadIdx.x;
  if (idx < 12288) {
    float s_ = bih0[idx % 192];
    for (int ks = 0; ks < 16; ++ks) s_ += part[ks * 12288 + idx];
    gi0[idx] = s_;
  }
}

// ---------------- fused 2-layer GRU, batch 1, weights in VGPRs ----------------
__global__ __launch_bounds__(192) void k_gru(const float* __restrict__ gi0,
                                             const float* __restrict__ Whh0,
                                             const float* __restrict__ bhh0,
                                             const float* __restrict__ Wih1,
                                             const float* __restrict__ Whh1,
                                             const float* __restrict__ bih1,
                                             const float* __restrict__ bhh1,
                                             float* __restrict__ out) {
  __shared__ float h0s[64], h1s[64], ys0s[64], gA[192], uA[192], vA[192];
  int g = threadIdx.x;
  float w0[64], wi1[64], wh1[64];
  #pragma unroll
  for (int k = 0; k < 16; ++k) {
    float4 t0 = ((const float4*)(Whh0 + (size_t)g * 64))[k];
    float4 t1 = ((const float4*)(Wih1 + (size_t)g * 64))[k];
    float4 t2 = ((const float4*)(Whh1 + (size_t)g * 64))[k];
    w0[k * 4] = t0.x; w0[k * 4 + 1] = t0.y; w0[k * 4 + 2] = t0.z; w0[k * 4 + 3] = t0.w;
    wi1[k * 4] = t1.x; wi1[k * 4 + 1] = t1.y; wi1[k * 4 + 2] = t1.z; wi1[k * 4 + 3] = t1.w;
    wh1[k * 4] = t2.x; wh1[k * 4 + 1] = t2.y; wh1[k * 4 + 2] = t2.z; wh1[k * 4 + 3] = t2.w;
  }
  float bh0 = bhh0[g], bi1 = bih1[g], bh1 = bhh1[g];
  if (g < 64) { h0s[g] = 0.f; h1s[g] = 0.f; }
  __syncthreads();
  for (int t = 0; t < 64; ++t) {
    float a0 = 0.f, a1 = 0.f, a2 = 0.f, a3 = 0.f;
    #pragma unroll
    for (int k = 0; k < 16; ++k) {
      float4 h4 = *(const float4*)&h0s[k * 4];
      a0 += w0[k * 4] * h4.x; a1 += w0[k * 4 + 1] * h4.y;
      a2 += w0[k * 4 + 2] * h4.z; a3 += w0[k * 4 + 3] * h4.w;
    }
    float gh = (a0 + a1) + (a2 + a3) + bh0;
    float giv = gi0[t * 192 + g];
    gA[g] = (g < 128) ? (giv + gh) : gh;
    __syncthreads();
    if (g < 64) {
      float r = 1.f / (1.f + expf(-gA[g]));
      float z = 1.f / (1.f + expf(-gA[g + 64]));
      float inn = gi0[t * 192 + 128 + g];
      float n = tanhf(inn + r * gA[g + 128]);
      float hnew = (1.f - z) * n + z * h0s[g];
      h0s[g] = hnew; ys0s[g] = hnew;
    }
    __syncthreads();
    float b0 = 0.f, b1_ = 0.f, b2_ = 0.f, b3 = 0.f;
    float c0 = 0.f, c1 = 0.f, c2 = 0.f, c3 = 0.f;
    #pragma unroll
    for (int k = 0; k < 16; ++k) {
      float4 y4 = *(const float4*)&ys0s[k * 4];
      float4 h4 = *(const float4*)&h1s[k * 4];
      b0 += wi1[k * 4] * y4.x; b1_ += wi1[k * 4 + 1] * y4.y;
      b2_ += wi1[k * 4 + 2] * y4.z; b3 += wi1[k * 4 + 3] * y4.w;
      c0 += wh1[k * 4] * h4.x; c1 += wh1[k * 4 + 1] * h4.y;
      c2 += wh1[k * 4 + 2] * h4.z; c3 += wh1[k * 4 + 3] * h4.w;
    }
    uA[g] = (b0 + b1_) + (b2_ + b3) + bi1;
    vA[g] = (c0 + c1) + (c2 + c3) + bh1;
    __syncthreads();
    if (g < 64) {
      float r = 1.f / (1.f + expf(-(uA[g] + vA[g])));
      float z = 1.f / (1.f + expf(-(uA[g + 64] + vA[g + 64])));
      float n = tanhf(uA[g + 128] + r * vA[g + 128]);
      float hnew = (1.f - z) * n + z * h1s[g];
      h1s[g] = hnew;
      out[t * 64 + g] = hnew;
    }
    __syncthreads();
  }
  if (g < 64) { out[4096 + g] = h0s[g]; out[4096 + 64 + g] = h1s[g]; }
}

extern "C" void kernel_launch(void* const* d_in, const int* in_sizes, int n_in,
                              void* d_out, int out_size, void* d_ws, size_t ws_size,
                              hipStream_t stream) {
  const float* x    = (const float*)d_in[0];
  const float* adj  = (const float*)d_in[1];
  const float* W1   = (const float*)d_in[2];
  const float* b1   = (const float*)d_in[3];
  const float* W2   = (const float*)d_in[4];
  const float* b2   = (const float*)d_in[5];
  const float* Wih0 = (const float*)d_in[6];
  const float* Whh0 = (const float*)d_in[7];
  const float* bih0 = (const float*)d_in[8];
  const float* bhh0 = (const float*)d_in[9];
  const float* Wih1 = (const float*)d_in[10];
  const float* Whh1 = (const float*)d_in[11];
  const float* bih1 = (const float*)d_in[12];
  const float* bhh1 = (const float*)d_in[13];
  float* out = (float*)d_out;

  char* ws = (char*)d_ws;
  // [0,32M): adjb ; [32M,64M): Bt (dead after gemm1), then Gp/Rm/part/gi0/B2t
  unsigned short* adjb = (unsigned short*)ws;
  unsigned short* Bt   = (unsigned short*)(ws + 33554432);
  float* Gp   = (float*)(ws + 33554432);              // 16MB (Bt dead after gemm1)
  float* Rm   = (float*)(ws + 50331648);              // 2MB
  float* part = (float*)(ws + 52428800);              // 768KB
  float* gi0  = (float*)(ws + 53215232);              // 48KB
  unsigned short* B2t = (unsigned short*)(ws + 53264384); // 1MB

  k_prep<<<8192, 256, 0, stream>>>(adj, adjb, x, W1, b1, Bt);
  k_gemm1_8ph<<<256, 512, 0, stream>>>(adjb, Bt, W2, b2, B2t);
  k_gemm2<<<256, 256, 0, stream>>>(adjb, B2t, Gp);
  k_lsm<<<128, 256, 0, stream>>>(Gp, Rm);
  k_gi0<<<768, 256, 0, stream>>>(Rm, Wih0, part);
  k_gi0red<<<48, 256, 0, stream>>>(part, bih0, gi0);
  k_gru<<<1, 192, 0, stream>>>(gi0, Whh0, bhh0, Wih1, Whh1, bih1, bhh1, out);
}